// Round 3
// baseline (154.984 us; speedup 1.0000x reference)
//
#include <hip/hip_runtime.h>

#define KS 3
#define OUTC 3
#define FEATC 6
#define PATCH (FEATC * KS * KS)  // 54

typedef float f32x4 __attribute__((ext_vector_type(4)));

// out[b,o,h,w] = sum_{c,dy,dx} feat[b,c,h+dy-1,w+dx-1] * km[b, o*54 + c*9 + dy*3 + dx, h, w]
//
// One thread: 4 consecutive pixels (w0..w0+3), one output channel o.
// vs R2:
//  - km fragment double-buffered (ka/kb): c+1's 9 nt loads are in flight
//    while c's FMAs run -> vmcnt queue never drains between c-iterations.
//  - feat boundary values (w0-1, w0+4) come from neighbor lanes via
//    __shfl_up/__shfl_down instead of 36 scalar VMEM loads; only lanes 0/63
//    do a predicated scalar load. Keeps the vmcnt stream = pure km.
__global__ __launch_bounds__(256) void supersample_kernel(
    const float* __restrict__ feat,
    const float* __restrict__ km,
    float* __restrict__ out,
    int B, int H, int W)
{
    const int Wq = W >> 2;
    const int total = B * OUTC * H * Wq;
    const int idx = blockIdx.x * blockDim.x + threadIdx.x;
    if (idx >= total) return;
    const int lane = threadIdx.x & 63;

    const int wq = idx % Wq;
    int t = idx / Wq;
    const int h = t % H;  t /= H;
    const int o = t % OUTC;
    const int b = t / OUTC;
    const int w0 = wq << 2;

    const size_t HW = (size_t)H * (size_t)W;
    const float* featb = feat + (size_t)b * FEATC * HW;
    const float* kmo   = km   + ((size_t)b * OUTC + o) * PATCH * HW
                               + (size_t)h * W + w0;
    float*       outp  = out  + ((size_t)b * OUTC + o) * HW + (size_t)h * W + w0;

    f32x4 acc = (f32x4)0.f;
    f32x4 ka[9], kb[9];

    // preload c=0 fragment
#pragma unroll
    for (int t9 = 0; t9 < 9; ++t9)
        ka[t9] = __builtin_nontemporal_load(
            reinterpret_cast<const f32x4*>(kmo + (size_t)t9 * HW));

    // One c-step: issue next fragment into NXT, build feat window, FMA CUR.
#define STEP(c, CUR, NXT)                                                      \
    {                                                                          \
        if ((c) + 1 < FEATC) {                                                 \
            const float* kmn = kmo + (size_t)(((c) + 1) * 9) * HW;             \
            _Pragma("unroll")                                                  \
            for (int t9 = 0; t9 < 9; ++t9)                                     \
                NXT[t9] = __builtin_nontemporal_load(                          \
                    reinterpret_cast<const f32x4*>(kmn + (size_t)t9 * HW));    \
        }                                                                      \
        float r[3][6];                                                         \
        _Pragma("unroll")                                                      \
        for (int ky = 0; ky < 3; ++ky) {                                       \
            const int hy = h + ky - 1;                                         \
            if (hy < 0 || hy >= H) {                                           \
                _Pragma("unroll")                                              \
                for (int j = 0; j < 6; ++j) r[ky][j] = 0.f;                    \
            } else {                                                           \
                const float* row = featb + (size_t)(c) * HW + (size_t)hy * W;  \
                const f32x4 mid = *reinterpret_cast<const f32x4*>(row + w0);   \
                float left  = __shfl_up(mid.w, 1);                             \
                float right = __shfl_down(mid.x, 1);                           \
                if (lane == 0)  left  = (w0 > 0)     ? row[w0 - 1] : 0.f;      \
                if (lane == 63) right = (w0 + 4 < W) ? row[w0 + 4] : 0.f;      \
                r[ky][0] = left;                                               \
                r[ky][1] = mid.x; r[ky][2] = mid.y;                            \
                r[ky][3] = mid.z; r[ky][4] = mid.w;                            \
                r[ky][5] = right;                                              \
            }                                                                  \
        }                                                                      \
        _Pragma("unroll")                                                      \
        for (int ky = 0; ky < 3; ++ky) {                                       \
            _Pragma("unroll")                                                  \
            for (int kx = 0; kx < 3; ++kx) {                                   \
                const f32x4 k = CUR[ky * 3 + kx];                              \
                acc.x = fmaf(r[ky][kx + 0], k.x, acc.x);                       \
                acc.y = fmaf(r[ky][kx + 1], k.y, acc.y);                       \
                acc.z = fmaf(r[ky][kx + 2], k.z, acc.z);                       \
                acc.w = fmaf(r[ky][kx + 3], k.w, acc.w);                       \
            }                                                                  \
        }                                                                      \
    }

    STEP(0, ka, kb)
    STEP(1, kb, ka)
    STEP(2, ka, kb)
    STEP(3, kb, ka)
    STEP(4, ka, kb)
    STEP(5, kb, ka)
#undef STEP

    *reinterpret_cast<f32x4*>(outp) = acc;
}

extern "C" void kernel_launch(void* const* d_in, const int* in_sizes, int n_in,
                              void* d_out, int out_size, void* d_ws, size_t ws_size,
                              hipStream_t stream) {
    const float* feat = (const float*)d_in[0];
    const float* km   = (const float*)d_in[1];
    float* out        = (float*)d_out;

    const int B = 4, H = 512, W = 512;
    const int total = B * OUTC * H * (W >> 2);
    const int block = 256;
    const int grid  = (total + block - 1) / block;
    supersample_kernel<<<grid, block, 0, stream>>>(feat, km, out, B, H, W);
}